// Round 1
// baseline (724.386 us; speedup 1.0000x reference)
//
#include <hip/hip_runtime.h>
#include <hip/hip_bf16.h>
#include <stdint.h>

typedef __bf16 bf16;
typedef bf16 bf16x8 __attribute__((ext_vector_type(8)));
typedef float f32x4 __attribute__((ext_vector_type(4)));

#define D 128

// ---------------- fused prep: transpose weights + zero signal + compact edges ----------------
__global__ void prep_compact_kernel(const float* __restrict__ V1, const float* __restrict__ W1,
                                    bf16* __restrict__ V1t, bf16* __restrict__ W1t,
                                    const int* __restrict__ ei, int E, int bs,
                                    int* __restrict__ count, int* __restrict__ list,
                                    float* __restrict__ signal) {
  int i = blockIdx.x * 256 + threadIdx.x;
  if (i < 384 * 384) { int k = i / 384, n = i % 384; V1t[n * 384 + k] = (bf16)V1[i]; }
  if (i < 128 * 128) { int k = i >> 7, n = i & 127;  W1t[n * 128 + k] = (bf16)W1[i]; }
  if (i < bs) signal[i] = 0.f;
  if (i < E && ei[i] < bs) {
    int p = atomicAdd(count, 1);   // compiler wave-aggregates this
    list[p] = i;
  }
}

// ---------------- node MLP: logits = relu(x@W1+b1)@W2 + b2 (unchanged) ----------------
__global__ __launch_bounds__(256, 2) void node_kernel(
    const float* __restrict__ x, const bf16* __restrict__ W1t,
    const float* __restrict__ b1, const float* __restrict__ W2,
    const float* __restrict__ b2, float* __restrict__ logits, int bs)
{
  __shared__ bf16 sA[64][136];
  __shared__ float sOut0[64], sOut1[64];

  int tid = threadIdx.x;
  if (tid < 64) { sOut0[tid] = 0.f; sOut1[tid] = 0.f; }

  {
    int g = tid >> 5, fl = tid & 31;
#pragma unroll
    for (int i = 0; i < 8; ++i) {
      int row = i * 8 + g;
      const float4* base = (const float4*)(x + (size_t)(blockIdx.x * 64 + row) * D);
      float4 v = base[fl];
      union { bf16 h[4]; uint2 u; } cv;
      cv.h[0] = (bf16)v.x; cv.h[1] = (bf16)v.y; cv.h[2] = (bf16)v.z; cv.h[3] = (bf16)v.w;
      *(uint2*)&sA[row][fl * 4] = cv.u;
    }
  }
  __syncthreads();

  int wave = tid >> 6, lane = tid & 63;
  int l15 = lane & 15, quad = lane >> 4;

  f32x4 acc[2][4];
#pragma unroll
  for (int ct = 0; ct < 2; ++ct)
#pragma unroll
    for (int rt = 0; rt < 4; ++rt)
      acc[ct][rt] = (f32x4){0.f, 0.f, 0.f, 0.f};

  for (int kc = 0; kc < 4; ++kc) {
    int k = kc * 32 + quad * 8;
    bf16x8 a[4], b[2];
#pragma unroll
    for (int rt = 0; rt < 4; ++rt)
      a[rt] = *(const bf16x8*)&sA[rt * 16 + l15][k];
#pragma unroll
    for (int ct = 0; ct < 2; ++ct)
      b[ct] = *(const bf16x8*)&W1t[(size_t)(wave * 32 + ct * 16 + l15) * 128 + k];
#pragma unroll
    for (int ct = 0; ct < 2; ++ct)
#pragma unroll
      for (int rt = 0; rt < 4; ++rt)
        acc[ct][rt] = __builtin_amdgcn_mfma_f32_16x16x32_bf16(a[rt], b[ct], acc[ct][rt], 0, 0, 0);
  }

  float bc[2], w0[2], w1[2];
#pragma unroll
  for (int ct = 0; ct < 2; ++ct) {
    int n = wave * 32 + ct * 16 + l15;
    bc[ct] = b1[n]; w0[ct] = W2[n * 2]; w1[ct] = W2[n * 2 + 1];
  }
#pragma unroll
  for (int rt = 0; rt < 4; ++rt) {
#pragma unroll
    for (int reg = 0; reg < 4; ++reg) {
      float p0 = 0.f, p1 = 0.f;
#pragma unroll
      for (int ct = 0; ct < 2; ++ct) {
        float h = fmaxf(acc[ct][rt][reg] + bc[ct], 0.f);
        p0 += h * w0[ct]; p1 += h * w1[ct];
      }
      p0 += __shfl_xor(p0, 1, 16); p0 += __shfl_xor(p0, 2, 16);
      p0 += __shfl_xor(p0, 4, 16); p0 += __shfl_xor(p0, 8, 16);
      p1 += __shfl_xor(p1, 1, 16); p1 += __shfl_xor(p1, 2, 16);
      p1 += __shfl_xor(p1, 4, 16); p1 += __shfl_xor(p1, 8, 16);
      if (l15 == 0) {
        int row = rt * 16 + quad * 4 + reg;
        atomicAdd(&sOut0[row], p0);
        atomicAdd(&sOut1[row], p1);
      }
    }
  }
  __syncthreads();
  if (tid < 64) {
    int node = blockIdx.x * 64 + tid;
    if (node < bs) {
      logits[2 * node]     = sOut0[tid] + b2[0];
      logits[2 * node + 1] = sOut1[tid] + b2[1];
    }
  }
}

// ---------------- pack: gather [x[src]|x[dst]|ea] -> pre-swizzled bf16 tiles ----------------
// Pure streaming kernel: tiny LDS, no MFMA -> high occupancy, deep load pipelining.
// Tile layout: 64 rows x 384 cols bf16 (768 B/row), byte addr XOR ((row&7)<<4)
// so the GEMM's ds_read_b128 A-fragments are bank-conflict-free after a LINEAR
// global_load_lds copy (swizzle on source + read side, linear LDS dest).
__global__ __launch_bounds__(256) void pack_kernel(
    const float* __restrict__ x, const float* __restrict__ ea,
    const int* __restrict__ ei, const int* __restrict__ count,
    const int* __restrict__ list, bf16* __restrict__ packed, int E)
{
  __shared__ int sSrc[64], sDst[64], sE[64];
  int nvalid = *count - (int)(blockIdx.x * 64);
  if (nvalid <= 0) return;                 // uniform exit before barrier
  if (nvalid > 64) nvalid = 64;

  int tid = threadIdx.x;
  if (tid < 64) {
    int e = 0;
    if (tid < nvalid) e = list[blockIdx.x * 64 + tid];
    sE[tid] = e; sSrc[tid] = ei[e]; sDst[tid] = ei[E + e];
  }
  __syncthreads();

  char* out = (char*)packed + (size_t)blockIdx.x * 49152;
  int g = tid >> 5, fl = tid & 31;

  // two passes of 12: batch-issue 12 loads (48 VGPR), then convert+store
#pragma unroll
  for (int half = 0; half < 2; ++half) {
    float4 buf[12];
#pragma unroll
    for (int j = 0; j < 12; ++j) {
      int t = (half * 12 + j) * 8 + g;     // 0..191 = 64 rows x 3 segments
      int row = t & 63, seg = t >> 6;
      const float* base;
      if (seg == 0)      base = x  + (size_t)sSrc[row] * D;
      else if (seg == 1) base = x  + (size_t)sDst[row] * D;
      else               base = ea + (size_t)sE[row]   * D;
      buf[j] = ((const float4*)base)[fl];
    }
#pragma unroll
    for (int j = 0; j < 12; ++j) {
      int t = (half * 12 + j) * 8 + g;
      int row = t & 63, seg = t >> 6;
      union { bf16 h[4]; uint2 u; } cv;
      cv.h[0] = (bf16)buf[j].x; cv.h[1] = (bf16)buf[j].y;
      cv.h[2] = (bf16)buf[j].z; cv.h[3] = (bf16)buf[j].w;
      int off = (row * 768 + seg * 256 + fl * 8) ^ ((row & 7) << 4);
      *(uint2*)(out + off) = cv.u;
    }
  }
}

// ---------------- edge GEMM over packed tiles + sigmoid + segment_max ----------------
__global__ __launch_bounds__(256, 2) void edge_gemm_kernel(
    const bf16* __restrict__ packed, const bf16* __restrict__ V1t,
    const float* __restrict__ bv1, const float* __restrict__ V2,
    const float* __restrict__ bv2, const int* __restrict__ ei,
    const int* __restrict__ count, const int* __restrict__ list,
    float* __restrict__ signal, int E)
{
  __shared__ __align__(16) char sA[49152];   // 64x384 bf16, swizzled layout
  __shared__ float sScore[64];
  __shared__ int sSrc[64];

  int nvalid = *count - (int)(blockIdx.x * 64);
  if (nvalid <= 0) return;                 // uniform exit before barrier
  if (nvalid > 64) nvalid = 64;

  int tid = threadIdx.x;
  int wave = tid >> 6, lane = tid & 63;

  // stage 48 KB tile: 12 x global_load_lds width=16, linear dest (source pre-swizzled)
  const char* tileb = (const char*)packed + (size_t)blockIdx.x * 49152;
#pragma unroll
  for (int i = 0; i < 12; ++i) {
    int off = i * 4096 + wave * 1024;      // wave-uniform LDS base; HW adds lane*16
    __builtin_amdgcn_global_load_lds(
        (const __attribute__((address_space(1))) unsigned int*)(tileb + off + lane * 16),
        (__attribute__((address_space(3))) unsigned int*)(sA + off),
        16, 0, 0);
  }

  if (tid < 64) {
    sScore[tid] = 0.f;
    int e = (tid < nvalid) ? list[blockIdx.x * 64 + tid] : 0;
    sSrc[tid] = ei[e];
  }

  asm volatile("s_waitcnt vmcnt(0)" ::: "memory");
  __syncthreads();

  int l15 = lane & 15, quad = lane >> 4;
  int xr = (l15 & 7) << 4;                 // per-thread row-XOR (rt*16 doesn't change row&7)

  f32x4 acc[6][4];
#pragma unroll
  for (int ct = 0; ct < 6; ++ct)
#pragma unroll
    for (int rt = 0; rt < 4; ++rt)
      acc[ct][rt] = (f32x4){0.f, 0.f, 0.f, 0.f};

  const bf16* Bbase = V1t + (size_t)(wave * 96 + l15) * 384 + quad * 8;

  for (int kc = 0; kc < 12; ++kc) {
    bf16x8 a[4], b[6];
#pragma unroll
    for (int rt = 0; rt < 4; ++rt) {
      int row = rt * 16 + l15;
      int off = (row * 768 + kc * 64 + quad * 16) ^ xr;
      a[rt] = *(const bf16x8*)(sA + off);
    }
#pragma unroll
    for (int ct = 0; ct < 6; ++ct)
      b[ct] = *(const bf16x8*)(Bbase + (size_t)ct * 16 * 384 + kc * 32);
#pragma unroll
    for (int ct = 0; ct < 6; ++ct)
#pragma unroll
      for (int rt = 0; rt < 4; ++rt)
        acc[ct][rt] = __builtin_amdgcn_mfma_f32_16x16x32_bf16(a[rt], b[ct], acc[ct][rt], 0, 0, 0);
  }

  // epilogue: +bv1, relu, dot V2, cross-lane reduce, sigmoid, atomicMax
  float bvc[6], v2c[6];
#pragma unroll
  for (int ct = 0; ct < 6; ++ct) {
    int n = wave * 96 + ct * 16 + l15;
    bvc[ct] = bv1[n]; v2c[ct] = V2[n];
  }
#pragma unroll
  for (int rt = 0; rt < 4; ++rt) {
#pragma unroll
    for (int reg = 0; reg < 4; ++reg) {
      float p = 0.f;
#pragma unroll
      for (int ct = 0; ct < 6; ++ct)
        p += fmaxf(acc[ct][rt][reg] + bvc[ct], 0.f) * v2c[ct];
      p += __shfl_xor(p, 1, 16);
      p += __shfl_xor(p, 2, 16);
      p += __shfl_xor(p, 4, 16);
      p += __shfl_xor(p, 8, 16);
      if (l15 == 0)
        atomicAdd(&sScore[rt * 16 + quad * 4 + reg], p);
    }
  }
  __syncthreads();
  if (tid < nvalid) {
    float sc = sScore[tid] + bv2[0];
    float sig = 1.f / (1.f + __expf(-sc));
    atomicMax((int*)&signal[sSrc[tid]], __float_as_int(sig));
  }
}

// ---------------- fallback fused edge kernel (used when ws too small for packed) ----------------
__global__ __launch_bounds__(256, 2) void edge_kernel(
    const float* __restrict__ x, const float* __restrict__ ea,
    const bf16* __restrict__ V1t, const float* __restrict__ bv1,
    const float* __restrict__ V2, const float* __restrict__ bv2,
    const int* __restrict__ ei, const int* __restrict__ count,
    const int* __restrict__ list, float* __restrict__ signal,
    int E, int bs)
{
  __shared__ bf16 sA[64][392];
  __shared__ float sScore[64];
  __shared__ int sSrc[64], sDst[64], sE[64];

  int nvalid = *count - (int)(blockIdx.x * 64);
  if (nvalid <= 0) return;
  if (nvalid > 64) nvalid = 64;

  int tid = threadIdx.x;
  if (tid < 64) {
    int e = 0;
    if (tid < nvalid) e = list[blockIdx.x * 64 + tid];
    sE[tid] = e;
    sSrc[tid] = ei[e];
    sDst[tid] = ei[E + e];
    sScore[tid] = 0.f;
  }
  __syncthreads();

  {
    int g = tid >> 5, fl = tid & 31;
#pragma unroll
    for (int i = 0; i < 24; ++i) {
      int t = i * 8 + g;
      int row = t & 63, seg = t >> 6;
      const float* base;
      if (seg == 0)      base = x  + (size_t)sSrc[row] * D;
      else if (seg == 1) base = x  + (size_t)sDst[row] * D;
      else               base = ea + (size_t)sE[row]   * D;
      float4 v = ((const float4*)base)[fl];
      union { bf16 h[4]; uint2 u; } cv;
      cv.h[0] = (bf16)v.x; cv.h[1] = (bf16)v.y; cv.h[2] = (bf16)v.z; cv.h[3] = (bf16)v.w;
      *(uint2*)&sA[row][seg * 128 + fl * 4] = cv.u;
    }
  }
  __syncthreads();

  int wave = tid >> 6, lane = tid & 63;
  int l15 = lane & 15, quad = lane >> 4;

  f32x4 acc[6][4];
#pragma unroll
  for (int ct = 0; ct < 6; ++ct)
#pragma unroll
    for (int rt = 0; rt < 4; ++rt)
      acc[ct][rt] = (f32x4){0.f, 0.f, 0.f, 0.f};

  const bf16* Bbase = V1t + (size_t)(wave * 96 + l15) * 384 + quad * 8;

  for (int kc = 0; kc < 12; ++kc) {
    int k = kc * 32 + quad * 8;
    bf16x8 a[4], b[6];
#pragma unroll
    for (int rt = 0; rt < 4; ++rt)
      a[rt] = *(const bf16x8*)&sA[rt * 16 + l15][k];
#pragma unroll
    for (int ct = 0; ct < 6; ++ct)
      b[ct] = *(const bf16x8*)(Bbase + (size_t)ct * 16 * 384 + kc * 32);
#pragma unroll
    for (int ct = 0; ct < 6; ++ct)
#pragma unroll
      for (int rt = 0; rt < 4; ++rt)
        acc[ct][rt] = __builtin_amdgcn_mfma_f32_16x16x32_bf16(a[rt], b[ct], acc[ct][rt], 0, 0, 0);
  }

  float bvc[6], v2c[6];
#pragma unroll
  for (int ct = 0; ct < 6; ++ct) {
    int n = wave * 96 + ct * 16 + l15;
    bvc[ct] = bv1[n]; v2c[ct] = V2[n];
  }
#pragma unroll
  for (int rt = 0; rt < 4; ++rt) {
#pragma unroll
    for (int reg = 0; reg < 4; ++reg) {
      float p = 0.f;
#pragma unroll
      for (int ct = 0; ct < 6; ++ct)
        p += fmaxf(acc[ct][rt][reg] + bvc[ct], 0.f) * v2c[ct];
      p += __shfl_xor(p, 1, 16);
      p += __shfl_xor(p, 2, 16);
      p += __shfl_xor(p, 4, 16);
      p += __shfl_xor(p, 8, 16);
      if (l15 == 0)
        atomicAdd(&sScore[rt * 16 + quad * 4 + reg], p);
    }
  }
  __syncthreads();
  if (tid < nvalid) {
    float sc = sScore[tid] + bv2[0];
    float sig = 1.f / (1.f + __expf(-sc));
    atomicMax((int*)&signal[sSrc[tid]], __float_as_int(sig));
  }
}

// ---------------- combine + labels ----------------
__global__ void combine_kernel(const float* __restrict__ logits, const float* __restrict__ signal,
                               const int* __restrict__ y, const float* __restrict__ ecw,
                               float* __restrict__ out, int bs) {
  int i = blockIdx.x * 256 + threadIdx.x;
  if (i < bs) {
    out[2 * i]     = logits[2 * i];
    out[2 * i + 1] = logits[2 * i + 1] + ecw[0] * signal[i];
    out[2 * bs + i] = (float)y[i];
  }
}

extern "C" void kernel_launch(void* const* d_in, const int* in_sizes, int n_in,
                              void* d_out, int out_size, void* d_ws, size_t ws_size,
                              hipStream_t stream) {
  const float* x   = (const float*)d_in[0];
  const float* ea  = (const float*)d_in[1];
  const float* W1  = (const float*)d_in[2];
  const float* b1  = (const float*)d_in[3];
  const float* W2  = (const float*)d_in[4];
  const float* b2  = (const float*)d_in[5];
  const float* V1  = (const float*)d_in[6];
  const float* bv1 = (const float*)d_in[7];
  const float* V2  = (const float*)d_in[8];
  const float* bv2 = (const float*)d_in[9];
  const float* ecw = (const float*)d_in[10];
  const int*   ei  = (const int*)d_in[11];
  const int*   y   = (const int*)d_in[12];

  int E  = in_sizes[1] / D;
  int bs = out_size / 3;

  char* ws = (char*)d_ws;
  size_t off = 0;
  auto rnd16 = [](size_t v) { return (v + 15) & ~(size_t)15; };
  bf16* V1t = (bf16*)(ws + off); off += (size_t)384 * 384 * 2;
  bf16* W1t = (bf16*)(ws + off); off += (size_t)128 * 128 * 2;
  float* signal = (float*)(ws + off); off += rnd16((size_t)bs * 4);
  float* logits = (float*)(ws + off); off += rnd16((size_t)bs * 8);
  int* count = (int*)(ws + off); off += 16;
  int* list  = (int*)(ws + off); off += rnd16((size_t)E * 4);

  int ntiles = (E + 63) / 64;
  bf16* packed = (bf16*)(ws + off);
  size_t need = off + (size_t)ntiles * 49152;
  bool split = (ws_size >= need);

  hipMemsetAsync(count, 0, 4, stream);

  int maxi = E;
  if (384 * 384 > maxi) maxi = 384 * 384;
  if (bs > maxi) maxi = bs;
  prep_compact_kernel<<<(maxi + 255) / 256, 256, 0, stream>>>(
      V1, W1, V1t, W1t, ei, E, bs, count, list, signal);

  if (split) {
    pack_kernel<<<ntiles, 256, 0, stream>>>(x, ea, ei, count, list, packed, E);
    edge_gemm_kernel<<<ntiles, 256, 0, stream>>>(packed, V1t, bv1, V2, bv2,
                                                 ei, count, list, signal, E);
    node_kernel<<<(bs + 63) / 64, 256, 0, stream>>>(x, W1t, b1, W2, b2, logits, bs);
  } else {
    node_kernel<<<(bs + 63) / 64, 256, 0, stream>>>(x, W1t, b1, W2, b2, logits, bs);
    edge_kernel<<<ntiles, 256, 0, stream>>>(x, ea, V1t, bv1, V2, bv2,
                                            ei, count, list, signal, E, bs);
  }
  combine_kernel<<<(bs + 255) / 256, 256, 0, stream>>>(logits, signal, y, ecw,
                                                       (float*)d_out, bs);
}